// Round 7
// baseline (115.407 us; speedup 1.0000x reference)
//
#include <hip/hip_runtime.h>
#include <math.h>

// Correctly-rounded double constants: Cj = cos(j*pi/16), N0 = sqrt(1/8).
#define C1 0.9807852804032304
#define C2 0.9238795325112867
#define C3 0.8314696123025452
#define C4 0.7071067811865476
#define C5 0.5555702330196022
#define C6 0.3826834323650898
#define C7 0.19509032201612825
#define N0 0.35355339059327373

// DCT-II matrix M[k][n] = norm_k * cos(pi/8*(n+0.5)*k), fully compile-time.
static constexpr double Mc[8][8] = {
 {  N0,      N0,      N0,      N0,      N0,      N0,      N0,      N0    },
 {  .5*C1,   .5*C3,   .5*C5,   .5*C7,  -.5*C7,  -.5*C5,  -.5*C3,  -.5*C1 },
 {  .5*C2,   .5*C6,  -.5*C6,  -.5*C2,  -.5*C2,  -.5*C6,   .5*C6,   .5*C2 },
 {  .5*C3,  -.5*C7,  -.5*C1,  -.5*C5,   .5*C5,   .5*C1,   .5*C7,  -.5*C3 },
 {  .5*C4,  -.5*C4,  -.5*C4,   .5*C4,   .5*C4,  -.5*C4,  -.5*C4,   .5*C4 },
 {  .5*C5,  -.5*C1,   .5*C7,   .5*C3,  -.5*C3,  -.5*C7,   .5*C1,  -.5*C5 },
 {  .5*C6,  -.5*C2,   .5*C2,  -.5*C6,  -.5*C6,   .5*C2,  -.5*C2,   .5*C6 },
 {  .5*C7,  -.5*C5,   .5*C3,  -.5*C1,   .5*C1,  -.5*C3,   .5*C5,  -.5*C7 },
};
// f32 copy for the post-quantization (smooth) path.
#define ROWF(r) {(float)Mc[r][0],(float)Mc[r][1],(float)Mc[r][2],(float)Mc[r][3],\
                 (float)Mc[r][4],(float)Mc[r][5],(float)Mc[r][6],(float)Mc[r][7]}
static constexpr float Mcf[8][8] = {ROWF(0),ROWF(1),ROWF(2),ROWF(3),ROWF(4),ROWF(5),ROWF(6),ROWF(7)};

// JPEG base quantization tables (exact integers)
static __device__ const double LUM_BASE[64] = {
 16,11,10,16,24,40,51,61,
 12,12,14,19,26,58,60,55,
 14,13,16,24,40,57,69,56,
 14,17,22,29,51,87,80,62,
 18,22,37,56,68,109,103,77,
 24,35,55,64,81,104,113,92,
 49,64,78,87,103,121,120,101,
 72,92,95,98,112,100,103,99};
static __device__ const double CHROM_BASE[64] = {
 17,18,24,47,99,99,99,99,
 18,21,26,66,99,99,99,99,
 24,26,56,99,99,99,99,99,
 47,66,99,99,99,99,99,99,
 99,99,99,99,99,99,99,99,
 99,99,99,99,99,99,99,99,
 99,99,99,99,99,99,99,99,
 99,99,99,99,99,99,99,99};

// One thread = one ROW of one 8x8 block of one channel (8 f64 in registers).
// Workgroup = 192 threads = 3 waves; wave w = channel w of an 8x64 strip.
// Pre-cliff (DCT+quant) f64, bit-identical to rounds 5/6; post-cliff f32.
// Round 7: transpose-2 and REC staging merged — each thread reads column rr
// of A3 for ALL 3 channels after one barrier and finishes IDCT+color in
// registers. LDS ops 48 -> 32 per thread, barriers 5 -> 4.
__global__ __launch_bounds__(192, 4) void jpeg_fwd(const float* __restrict__ img,
                                                   const int* __restrict__ quality,
                                                   float* __restrict__ out)
{
    __shared__ double QT[128];     // [2][8][8] scaled quant tables, f64
    __shared__ double U[1728];     // 13824 B union region
    double* TR1 = U;                       // [3][576] f64  (transpose-1)
    float*  TR2 = (float*)U;               // [3][576] f32  (transpose-2, bytes 0..6912)

    const int t   = threadIdx.x;
    const int w   = t >> 6;      // channel = wave id (wave-uniform)
    const int l   = t & 63;
    const int blk = l >> 3;      // block within strip (0..7)
    const int rr  = l & 7;       // row within block

    const int b    = blockIdx.x >> 9;   // image index
    const int rem  = blockIdx.x & 511;
    const int row0 = (rem >> 3) << 3;   // strip row * 8
    const int col0 = (rem & 7) << 6;    // strip col * 64

    const size_t plane = 512 * 512;

    // ---- Issue global loads early (my row's 8 px, all 3 planes, float4)
    const float* p = img + (size_t)(b * 3) * plane + (size_t)(row0 + rr) * 512 + col0 + blk * 8;
    float4 R0 = *(const float4*)(p);
    float4 R1 = *(const float4*)(p + 4);
    float4 G0 = *(const float4*)(p + plane);
    float4 G1 = *(const float4*)(p + plane + 4);
    float4 B0 = *(const float4*)(p + 2 * plane);
    float4 B1 = *(const float4*)(p + 2 * plane + 4);

    // ---- Build quant tables in LDS (f64, same arithmetic as passing rounds)
    if (t < 128) {
        int tbl = t >> 6, e = t & 63;
        int q   = quality[0];
        q = q < 1 ? 1 : (q > 100 ? 100 : q);
        double scale = (q < 50) ? (5000.0 / (double)q) : (200.0 - 2.0 * (double)q);
        double base  = tbl ? CHROM_BASE[e] : LUM_BASE[e];
        double v = (base * scale + 50.0) / 100.0;
        QT[t] = fmin(fmax(v, 1.0), 255.0);
    }
    __syncthreads();

    // Exact f64 YCbCr weights (identical expressions to the passing R2 kernel)
    const double W00 =  0.299,   W01 =  0.587,   W02 =  0.114;
    const double W10 = -0.1687,  W11 = -0.3313,  W12 =  0.5;
    const double W20 =  0.5,     W21 = -0.4187,  W22 = -0.0813;

    float rf[8] = {R0.x, R0.y, R0.z, R0.w, R1.x, R1.y, R1.z, R1.w};
    float gf[8] = {G0.x, G0.y, G0.z, G0.w, G1.x, G1.y, G1.z, G1.w};
    float bf[8] = {B0.x, B0.y, B0.z, B0.w, B1.x, B1.y, B1.z, B1.w};

    // ---- Color convert (my channel only), -128  [pre-cliff: f64, unchanged]
    double row[8];
    #pragma unroll
    for (int k = 0; k < 8; ++k) {
        double rv = (double)rf[k] * 255.0;
        double gv = (double)gf[k] * 255.0;
        double bv = (double)bf[k] * 255.0;
        double v;
        if (w == 0)      v = W00 * rv + W01 * gv + W02 * bv;
        else if (w == 1) v = W10 * rv + W11 * gv + W12 * bv + 128.0;
        else             v = W20 * rv + W21 * gv + W22 * bv + 128.0;
        row[k] = v - 128.0;
    }

    // ---- P1: row @ M^T  [pre-cliff: f64, unchanged product order]
    double y[8];
    #pragma unroll
    for (int c = 0; c < 8; ++c) {
        double s = 0.0;
        #pragma unroll
        for (int k = 0; k < 8; ++k)
            s += row[k] * Mc[c][k];
        y[c] = s;
    }

    // ---- Transpose 1 (f64, pad-9 layout)
    {
        double* tb = TR1 + w * 576 + blk * 72 + rr * 9;
        #pragma unroll
        for (int k = 0; k < 8; ++k) tb[k] = y[k];
    }
    __syncthreads();
    double t1[8], qv[8];
    {
        const double* tb = TR1 + w * 576 + blk * 72 + rr;
        #pragma unroll
        for (int k = 0; k < 8; ++k) t1[k] = tb[k * 9];
    }
    const int sel = ((b * 3 + w) < 16) ? 0 : 1;   // reference's flattened-index quirk
    #pragma unroll
    for (int j = 0; j < 8; ++j) qv[j] = QT[(sel << 6) + (j << 3) + rr];

    // ---- P2: column DCT + quantize  tq = rint(dct/q)*q  [pre-cliff: unchanged]
    double wq[8];
    #pragma unroll
    for (int j = 0; j < 8; ++j) {
        double s = 0.0;
        #pragma unroll
        for (int k = 0; k < 8; ++k)
            s += t1[k] * Mc[j][k];
        wq[j] = rint(s / qv[j]) * qv[j];   // round half-to-even, like jnp.round
    }

    // ======== post-cliff: f32 from here on ========
    float wqf[8];
    #pragma unroll
    for (int k = 0; k < 8; ++k) wqf[k] = (float)wq[k];

    // ---- P3: (tq^T row) @ M  (f32)  — rows of A3 = tq^T M
    float a3[8];
    #pragma unroll
    for (int j = 0; j < 8; ++j) {
        float s = 0.0f;
        #pragma unroll
        for (int k = 0; k < 8; ++k)
            s += wqf[k] * Mcf[k][j];
        a3[j] = s;
    }

    // ---- Transpose 2 write (f32, pad-9, reuses transpose-1 bytes)
    __syncthreads();   // all TR1 reads complete before TR2 writes
    {
        float* tb = TR2 + w * 576 + blk * 72 + rr * 9;
        #pragma unroll
        for (int k = 0; k < 8; ++k) tb[k] = a3[k];
    }
    __syncthreads();

    // ---- Read column rr of A3 for ALL 3 channels (stride-9 f32: 2 lanes/bank, free)
    float tY[8], tU[8], tV[8];
    {
        const float* t0 = TR2 + 0 * 576 + blk * 72 + rr;
        const float* u0 = TR2 + 1 * 576 + blk * 72 + rr;
        const float* v0 = TR2 + 2 * 576 + blk * 72 + rr;
        #pragma unroll
        for (int k = 0; k < 8; ++k) {
            tY[k] = t0[k * 9];
            tU[k] = u0[k * 9];
            tV[k] = v0[k * 9];
        }
    }

    // ---- P4 (f32): final IDCT row rr for Y, Cb, Cr (centered, +128 folded into mix)
    // idct[rr][j] = sum_k A3[k][rr] * M[k][j]
    float yr[8], ur[8], vr[8];
    #pragma unroll
    for (int j = 0; j < 8; ++j) {
        float sy = 0.0f, su = 0.0f, sv = 0.0f;
        #pragma unroll
        for (int k = 0; k < 8; ++k) {
            sy += tY[k] * Mcf[k][j];
            su += tU[k] * Mcf[k][j];
            sv += tV[k] * Mcf[k][j];
        }
        yr[j] = sy; ur[j] = su; vr[j] = sv;
    }

    // ---- Color back (f32, my wave writes plane w), /255, clip, coalesced store
    // rec_Y = yr+128; cb = (ur+128)-128 = ur; cr = vr.
    float* q0 = out + (size_t)(b * 3 + w) * plane + (size_t)(row0 + rr) * 512 + col0 + blk * 8;
    float o[8];
    #pragma unroll
    for (int k = 0; k < 8; ++k) {
        float yd = yr[k] + 128.0f;
        float v;
        if (w == 0)      v = yd + 1.402f * vr[k];
        else if (w == 1) v = yd - 0.34414f * ur[k] - 0.71414f * vr[k];
        else             v = yd + 1.772f * ur[k];
        o[k] = fminf(fmaxf(v * (1.0f / 255.0f), 0.0f), 1.0f);
    }
    *(float4*)(q0)     = make_float4(o[0], o[1], o[2], o[3]);
    *(float4*)(q0 + 4) = make_float4(o[4], o[5], o[6], o[7]);
}

extern "C" void kernel_launch(void* const* d_in, const int* in_sizes, int n_in,
                              void* d_out, int out_size, void* d_ws, size_t ws_size,
                              hipStream_t stream) {
    const float* img     = (const float*)d_in[0];
    const int*   quality = (const int*)d_in[1];
    float*       out     = (float*)d_out;
    // 16 images x 64 row-strips x 8 col-strips = 8192 workgroups x 192 threads
    jpeg_fwd<<<8192, 192, 0, stream>>>(img, quality, out);
}

// Round 8
// 113.042 us; speedup vs baseline: 1.0209x; 1.0209x over previous
//
#include <hip/hip_runtime.h>
#include <math.h>

// Correctly-rounded double constants: Cj = cos(j*pi/16), N0 = sqrt(1/8).
#define C1 0.9807852804032304
#define C2 0.9238795325112867
#define C3 0.8314696123025452
#define C4 0.7071067811865476
#define C5 0.5555702330196022
#define C6 0.3826834323650898
#define C7 0.19509032201612825
#define N0 0.35355339059327373

// DCT-II matrix M[k][n] = norm_k * cos(pi/8*(n+0.5)*k), fully compile-time.
static constexpr double Mc[8][8] = {
 {  N0,      N0,      N0,      N0,      N0,      N0,      N0,      N0    },
 {  .5*C1,   .5*C3,   .5*C5,   .5*C7,  -.5*C7,  -.5*C5,  -.5*C3,  -.5*C1 },
 {  .5*C2,   .5*C6,  -.5*C6,  -.5*C2,  -.5*C2,  -.5*C6,   .5*C6,   .5*C2 },
 {  .5*C3,  -.5*C7,  -.5*C1,  -.5*C5,   .5*C5,   .5*C1,   .5*C7,  -.5*C3 },
 {  .5*C4,  -.5*C4,  -.5*C4,   .5*C4,   .5*C4,  -.5*C4,  -.5*C4,   .5*C4 },
 {  .5*C5,  -.5*C1,   .5*C7,   .5*C3,  -.5*C3,  -.5*C7,   .5*C1,  -.5*C5 },
 {  .5*C6,  -.5*C2,   .5*C2,  -.5*C6,  -.5*C6,   .5*C2,  -.5*C2,   .5*C6 },
 {  .5*C7,  -.5*C5,   .5*C3,  -.5*C1,   .5*C1,  -.5*C3,   .5*C5,  -.5*C7 },
};
// f32 copy for the post-quantization (smooth) path.
#define ROWF(r) {(float)Mc[r][0],(float)Mc[r][1],(float)Mc[r][2],(float)Mc[r][3],\
                 (float)Mc[r][4],(float)Mc[r][5],(float)Mc[r][6],(float)Mc[r][7]}
static constexpr float Mcf[8][8] = {ROWF(0),ROWF(1),ROWF(2),ROWF(3),ROWF(4),ROWF(5),ROWF(6),ROWF(7)};

// JPEG base quantization tables (exact integers)
static __device__ const double LUM_BASE[64] = {
 16,11,10,16,24,40,51,61,
 12,12,14,19,26,58,60,55,
 14,13,16,24,40,57,69,56,
 14,17,22,29,51,87,80,62,
 18,22,37,56,68,109,103,77,
 24,35,55,64,81,104,113,92,
 49,64,78,87,103,121,120,101,
 72,92,95,98,112,100,103,99};
static __device__ const double CHROM_BASE[64] = {
 17,18,24,47,99,99,99,99,
 18,21,26,66,99,99,99,99,
 24,26,56,99,99,99,99,99,
 47,66,99,99,99,99,99,99,
 99,99,99,99,99,99,99,99,
 99,99,99,99,99,99,99,99,
 99,99,99,99,99,99,99,99,
 99,99,99,99,99,99,99,99};

// One thread = one ROW of one 8x8 block of one channel (8 f64 in registers).
// Workgroup = 192 threads = 3 waves; wave w = channel w of an 8x64 strip.
// Pre-cliff (DCT+quant) f64, bit-identical to rounds 5-7; post-cliff f32.
// Round 8: barriers 4 -> 1. T1 transpose is in-wave (8-lane groups, compiler
// lgkmcnt orders same-wave LDS RAW); QT is built redundantly by every wave
// (benign race, byte-identical values); TR2 (f32) aliases each wave's OWN
// f64 TR1 chunk (in-order DS pipe handles same-wave WAR). The single
// remaining barrier protects the only cross-wave dependency: the final
// 3-channel column read for IDCT+color.
__global__ __launch_bounds__(192, 4) void jpeg_fwd(const float* __restrict__ img,
                                                   const int* __restrict__ quality,
                                                   float* __restrict__ out)
{
    __shared__ double QT[128];     // [2][8][8] scaled quant tables, f64
    __shared__ double U[1728];     // 13824 B; per-wave chunk = U + w*576 (4608 B)

    const int t   = threadIdx.x;
    const int w   = t >> 6;      // channel = wave id (wave-uniform)
    const int l   = t & 63;
    const int blk = l >> 3;      // block within strip (0..7)
    const int rr  = l & 7;       // row within block

    const int b    = blockIdx.x >> 9;   // image index
    const int rem  = blockIdx.x & 511;
    const int row0 = (rem >> 3) << 3;   // strip row * 8
    const int col0 = (rem & 7) << 6;    // strip col * 64

    const size_t plane = 512 * 512;

    // ---- Issue global loads early (my row's 8 px, all 3 planes, float4)
    const float* p = img + (size_t)(b * 3) * plane + (size_t)(row0 + rr) * 512 + col0 + blk * 8;
    float4 R0 = *(const float4*)(p);
    float4 R1 = *(const float4*)(p + 4);
    float4 G0 = *(const float4*)(p + plane);
    float4 G1 = *(const float4*)(p + plane + 4);
    float4 B0 = *(const float4*)(p + 2 * plane);
    float4 B1 = *(const float4*)(p + 2 * plane + 4);

    // ---- Build quant tables in LDS — EVERY wave writes all 128 entries with
    // identical values (benign race); own-wave RAW ordered by lgkmcnt.
    {
        int q = quality[0];
        q = q < 1 ? 1 : (q > 100 ? 100 : q);
        double scale = (q < 50) ? (5000.0 / (double)q) : (200.0 - 2.0 * (double)q);
        #pragma unroll
        for (int h = 0; h < 2; ++h) {
            int e = l + (h << 6);           // entries l and l+64 -> covers 0..127
            int tbl = e >> 6, idx = e & 63;
            double base = tbl ? CHROM_BASE[idx] : LUM_BASE[idx];
            double v = (base * scale + 50.0) / 100.0;
            QT[e] = fmin(fmax(v, 1.0), 255.0);
        }
    }

    // Exact f64 YCbCr weights (identical expressions to the passing R2 kernel)
    const double W00 =  0.299,   W01 =  0.587,   W02 =  0.114;
    const double W10 = -0.1687,  W11 = -0.3313,  W12 =  0.5;
    const double W20 =  0.5,     W21 = -0.4187,  W22 = -0.0813;

    float rf[8] = {R0.x, R0.y, R0.z, R0.w, R1.x, R1.y, R1.z, R1.w};
    float gf[8] = {G0.x, G0.y, G0.z, G0.w, G1.x, G1.y, G1.z, G1.w};
    float bf[8] = {B0.x, B0.y, B0.z, B0.w, B1.x, B1.y, B1.z, B1.w};

    // ---- Color convert (my channel only), -128  [pre-cliff: f64, unchanged]
    double row[8];
    #pragma unroll
    for (int k = 0; k < 8; ++k) {
        double rv = (double)rf[k] * 255.0;
        double gv = (double)gf[k] * 255.0;
        double bv = (double)bf[k] * 255.0;
        double v;
        if (w == 0)      v = W00 * rv + W01 * gv + W02 * bv;
        else if (w == 1) v = W10 * rv + W11 * gv + W12 * bv + 128.0;
        else             v = W20 * rv + W21 * gv + W22 * bv + 128.0;
        row[k] = v - 128.0;
    }

    // ---- P1: row @ M^T  [pre-cliff: f64, unchanged product order]
    double y[8];
    #pragma unroll
    for (int c = 0; c < 8; ++c) {
        double s = 0.0;
        #pragma unroll
        for (int k = 0; k < 8; ++k)
            s += row[k] * Mc[c][k];
        y[c] = s;
    }

    // ---- Transpose 1 (f64, pad-9, own-wave chunk — IN-WAVE, no barrier)
    {
        double* tb = U + w * 576 + blk * 72 + rr * 9;
        #pragma unroll
        for (int k = 0; k < 8; ++k) tb[k] = y[k];
    }
    double t1[8], qv[8];
    {
        const double* tb = U + w * 576 + blk * 72 + rr;
        #pragma unroll
        for (int k = 0; k < 8; ++k) t1[k] = tb[k * 9];
    }
    const int sel = ((b * 3 + w) < 16) ? 0 : 1;   // reference's flattened-index quirk
    #pragma unroll
    for (int j = 0; j < 8; ++j) qv[j] = QT[(sel << 6) + (j << 3) + rr];

    // ---- P2: column DCT + quantize  tq = rint(dct/q)*q  [pre-cliff: unchanged]
    double wq[8];
    #pragma unroll
    for (int j = 0; j < 8; ++j) {
        double s = 0.0;
        #pragma unroll
        for (int k = 0; k < 8; ++k)
            s += t1[k] * Mc[j][k];
        wq[j] = rint(s / qv[j]) * qv[j];   // round half-to-even, like jnp.round
    }

    // ======== post-cliff: f32 from here on ========
    float wqf[8];
    #pragma unroll
    for (int k = 0; k < 8; ++k) wqf[k] = (float)wq[k];

    // ---- P3: (tq^T row) @ M  (f32)  — rows of A3 = tq^T M
    float a3[8];
    #pragma unroll
    for (int j = 0; j < 8; ++j) {
        float s = 0.0f;
        #pragma unroll
        for (int k = 0; k < 8; ++k)
            s += wqf[k] * Mcf[k][j];
        a3[j] = s;
    }

    // ---- Transpose 2 write (f32, pad-9) into MY OWN wave's chunk
    // (same-wave WAR with T1 reads above: in-order DS pipe, no barrier)
    {
        float* tb = (float*)(U + w * 576) + blk * 72 + rr * 9;
        #pragma unroll
        for (int k = 0; k < 8; ++k) tb[k] = a3[k];
    }
    __syncthreads();   // the ONLY barrier: cross-wave channel exchange below

    // ---- Read column rr of A3 for ALL 3 channels (stride-9 f32: 2 lanes/bank, free)
    float tY[8], tU[8], tV[8];
    {
        const float* c0 = (float*)(U + 0 * 576) + blk * 72 + rr;
        const float* c1 = (float*)(U + 1 * 576) + blk * 72 + rr;
        const float* c2 = (float*)(U + 2 * 576) + blk * 72 + rr;
        #pragma unroll
        for (int k = 0; k < 8; ++k) {
            tY[k] = c0[k * 9];
            tU[k] = c1[k * 9];
            tV[k] = c2[k * 9];
        }
    }

    // ---- P4 (f32): final IDCT row rr for Y, Cb, Cr (centered; +128 folded into mix)
    float yr[8], ur[8], vr[8];
    #pragma unroll
    for (int j = 0; j < 8; ++j) {
        float sy = 0.0f, su = 0.0f, sv = 0.0f;
        #pragma unroll
        for (int k = 0; k < 8; ++k) {
            sy += tY[k] * Mcf[k][j];
            su += tU[k] * Mcf[k][j];
            sv += tV[k] * Mcf[k][j];
        }
        yr[j] = sy; ur[j] = su; vr[j] = sv;
    }

    // ---- Color back (f32, my wave writes plane w), /255, clip, coalesced store
    float* q0 = out + (size_t)(b * 3 + w) * plane + (size_t)(row0 + rr) * 512 + col0 + blk * 8;
    float o[8];
    #pragma unroll
    for (int k = 0; k < 8; ++k) {
        float yd = yr[k] + 128.0f;
        float v;
        if (w == 0)      v = yd + 1.402f * vr[k];
        else if (w == 1) v = yd - 0.34414f * ur[k] - 0.71414f * vr[k];
        else             v = yd + 1.772f * ur[k];
        o[k] = fminf(fmaxf(v * (1.0f / 255.0f), 0.0f), 1.0f);
    }
    *(float4*)(q0)     = make_float4(o[0], o[1], o[2], o[3]);
    *(float4*)(q0 + 4) = make_float4(o[4], o[5], o[6], o[7]);
}

extern "C" void kernel_launch(void* const* d_in, const int* in_sizes, int n_in,
                              void* d_out, int out_size, void* d_ws, size_t ws_size,
                              hipStream_t stream) {
    const float* img     = (const float*)d_in[0];
    const int*   quality = (const int*)d_in[1];
    float*       out     = (float*)d_out;
    // 16 images x 64 row-strips x 8 col-strips = 8192 workgroups x 192 threads
    jpeg_fwd<<<8192, 192, 0, stream>>>(img, quality, out);
}

// Round 9
// 111.123 us; speedup vs baseline: 1.0385x; 1.0173x over previous
//
#include <hip/hip_runtime.h>
#include <math.h>

// Correctly-rounded double constants: Cj = cos(j*pi/16), N0 = sqrt(1/8).
#define C1 0.9807852804032304
#define C2 0.9238795325112867
#define C3 0.8314696123025452
#define C4 0.7071067811865476
#define C5 0.5555702330196022
#define C6 0.3826834323650898
#define C7 0.19509032201612825
#define N0 0.35355339059327373

// DCT-II matrix M[k][n] = norm_k * cos(pi/8*(n+0.5)*k), fully compile-time.
static constexpr double Mc[8][8] = {
 {  N0,      N0,      N0,      N0,      N0,      N0,      N0,      N0    },
 {  .5*C1,   .5*C3,   .5*C5,   .5*C7,  -.5*C7,  -.5*C5,  -.5*C3,  -.5*C1 },
 {  .5*C2,   .5*C6,  -.5*C6,  -.5*C2,  -.5*C2,  -.5*C6,   .5*C6,   .5*C2 },
 {  .5*C3,  -.5*C7,  -.5*C1,  -.5*C5,   .5*C5,   .5*C1,   .5*C7,  -.5*C3 },
 {  .5*C4,  -.5*C4,  -.5*C4,   .5*C4,   .5*C4,  -.5*C4,  -.5*C4,   .5*C4 },
 {  .5*C5,  -.5*C1,   .5*C7,   .5*C3,  -.5*C3,  -.5*C7,   .5*C1,  -.5*C5 },
 {  .5*C6,  -.5*C2,   .5*C2,  -.5*C6,  -.5*C6,   .5*C2,  -.5*C2,   .5*C6 },
 {  .5*C7,  -.5*C5,   .5*C3,  -.5*C1,   .5*C1,  -.5*C3,   .5*C5,  -.5*C7 },
};
// f32 copy for the post-quantization (smooth) path.
#define ROWF(r) {(float)Mc[r][0],(float)Mc[r][1],(float)Mc[r][2],(float)Mc[r][3],\
                 (float)Mc[r][4],(float)Mc[r][5],(float)Mc[r][6],(float)Mc[r][7]}
static constexpr float Mcf[8][8] = {ROWF(0),ROWF(1),ROWF(2),ROWF(3),ROWF(4),ROWF(5),ROWF(6),ROWF(7)};

// JPEG base quantization tables (exact integers)
static __device__ const double LUM_BASE[64] = {
 16,11,10,16,24,40,51,61,
 12,12,14,19,26,58,60,55,
 14,13,16,24,40,57,69,56,
 14,17,22,29,51,87,80,62,
 18,22,37,56,68,109,103,77,
 24,35,55,64,81,104,113,92,
 49,64,78,87,103,121,120,101,
 72,92,95,98,112,100,103,99};
static __device__ const double CHROM_BASE[64] = {
 17,18,24,47,99,99,99,99,
 18,21,26,66,99,99,99,99,
 24,26,56,99,99,99,99,99,
 47,66,99,99,99,99,99,99,
 99,99,99,99,99,99,99,99,
 99,99,99,99,99,99,99,99,
 99,99,99,99,99,99,99,99,
 99,99,99,99,99,99,99,99};

// One thread = one ROW of one 8x8 block of one channel.
// Workgroup = 192 threads = 3 waves; wave w = channel w of an 8x64 strip.
// Pre-cliff (DCT+quant) f64; post-cliff f32. Single barrier (R8 structure).
// Round 9: (1) f64 div -> reciprocal + fma refinement (bit-identical),
// (2) even-odd symmetry decomposition of all 8-point transforms (64->40 ops),
// (3) x255 folded into YCbCr weights at compile time.
__global__ __launch_bounds__(192, 4) void jpeg_fwd(const float* __restrict__ img,
                                                   const int* __restrict__ quality,
                                                   float* __restrict__ out)
{
    __shared__ double QT[128];     // [2][8][8] scaled quant tables, f64
    __shared__ double RQ[128];     // reciprocals 1/QT (correctly rounded)
    __shared__ double U[1728];     // 13824 B; per-wave chunk = U + w*576 (4608 B)

    const int t   = threadIdx.x;
    const int w   = t >> 6;      // channel = wave id (wave-uniform)
    const int l   = t & 63;
    const int blk = l >> 3;      // block within strip (0..7)
    const int rr  = l & 7;       // row within block

    const int b    = blockIdx.x >> 9;   // image index
    const int rem  = blockIdx.x & 511;
    const int row0 = (rem >> 3) << 3;   // strip row * 8
    const int col0 = (rem & 7) << 6;    // strip col * 64

    const size_t plane = 512 * 512;

    // ---- Issue global loads early (my row's 8 px, all 3 planes, float4)
    const float* p = img + (size_t)(b * 3) * plane + (size_t)(row0 + rr) * 512 + col0 + blk * 8;
    float4 R0 = *(const float4*)(p);
    float4 R1 = *(const float4*)(p + 4);
    float4 G0 = *(const float4*)(p + plane);
    float4 G1 = *(const float4*)(p + plane + 4);
    float4 B0 = *(const float4*)(p + 2 * plane);
    float4 B1 = *(const float4*)(p + 2 * plane + 4);

    // ---- Build quant tables + reciprocals in LDS — EVERY wave writes all 128
    // entries with identical values (benign race); own-wave RAW via lgkmcnt.
    {
        int q = quality[0];
        q = q < 1 ? 1 : (q > 100 ? 100 : q);
        double scale = (q < 50) ? (5000.0 / (double)q) : (200.0 - 2.0 * (double)q);
        #pragma unroll
        for (int h = 0; h < 2; ++h) {
            int e = l + (h << 6);           // entries l and l+64 -> covers 0..127
            int tbl = e >> 6, idx = e & 63;
            double base = tbl ? CHROM_BASE[idx] : LUM_BASE[idx];
            double v = (base * scale + 50.0) / 100.0;
            v = fmin(fmax(v, 1.0), 255.0);
            QT[e] = v;
            RQ[e] = 1.0 / v;
        }
    }

    // YCbCr weights with x255 folded in at compile time (f64 products).
    const double F00 =  0.299 * 255.0,  F01 =  0.587 * 255.0,  F02 =  0.114 * 255.0;
    const double F10 = -0.1687 * 255.0, F11 = -0.3313 * 255.0, F12 =  0.5 * 255.0;
    const double F20 =  0.5 * 255.0,    F21 = -0.4187 * 255.0, F22 = -0.0813 * 255.0;

    float rf[8] = {R0.x, R0.y, R0.z, R0.w, R1.x, R1.y, R1.z, R1.w};
    float gf[8] = {G0.x, G0.y, G0.z, G0.w, G1.x, G1.y, G1.z, G1.w};
    float bf[8] = {B0.x, B0.y, B0.z, B0.w, B1.x, B1.y, B1.z, B1.w};

    // ---- Color convert (my channel only); keep +128 then -128 (both
    // roundings, matching np) — they do NOT cancel exactly in f64.
    double row[8];
    #pragma unroll
    for (int k = 0; k < 8; ++k) {
        double rv = (double)rf[k];
        double gv = (double)gf[k];
        double bv = (double)bf[k];
        double v;
        if (w == 0)      v = F00 * rv + F01 * gv + F02 * bv;
        else if (w == 1) v = F10 * rv + F11 * gv + F12 * bv + 128.0;
        else             v = F20 * rv + F21 * gv + F22 * bv + 128.0;
        row[k] = v - 128.0;
    }

    // ---- P1: row @ M^T via even-odd symmetry (f64, 8 add + 32 FMA)
    // y[c] = sum_{k=0..3} (row[k] + (-1)^c row[7-k]) * Mc[c][k]
    double y[8];
    {
        double u0[4], v0[4];
        #pragma unroll
        for (int k = 0; k < 4; ++k) {
            u0[k] = row[k] + row[7 - k];
            v0[k] = row[k] - row[7 - k];
        }
        #pragma unroll
        for (int c = 0; c < 8; c += 2) {
            double se = 0.0, so = 0.0;
            #pragma unroll
            for (int k = 0; k < 4; ++k) {
                se += u0[k] * Mc[c][k];
                so += v0[k] * Mc[c + 1][k];
            }
            y[c] = se; y[c + 1] = so;
        }
    }

    // ---- Transpose 1 (f64, pad-9, own-wave chunk — IN-WAVE, no barrier)
    {
        double* tb = U + w * 576 + blk * 72 + rr * 9;
        #pragma unroll
        for (int k = 0; k < 8; ++k) tb[k] = y[k];
    }
    double t1[8], qv[8], rv8[8];
    {
        const double* tb = U + w * 576 + blk * 72 + rr;
        #pragma unroll
        for (int k = 0; k < 8; ++k) t1[k] = tb[k * 9];
    }
    const int sel = ((b * 3 + w) < 16) ? 0 : 1;   // reference's flattened-index quirk
    #pragma unroll
    for (int j = 0; j < 8; ++j) {
        qv[j]  = QT[(sel << 6) + (j << 3) + rr];
        rv8[j] = RQ[(sel << 6) + (j << 3) + rr];
    }

    // ---- P2: column DCT (even-odd) + quantize tq = rint(s/q)*q.
    // Division via reciprocal + one fma refinement: correctly rounded,
    // bit-identical to hardware s/q (Markstein).
    double wq[8];
    {
        double tu[4], tv[4];
        #pragma unroll
        for (int k = 0; k < 4; ++k) {
            tu[k] = t1[k] + t1[7 - k];
            tv[k] = t1[k] - t1[7 - k];
        }
        #pragma unroll
        for (int j = 0; j < 8; j += 2) {
            double se = 0.0, so = 0.0;
            #pragma unroll
            for (int k = 0; k < 4; ++k) {
                se += tu[k] * Mc[j][k];
                so += tv[k] * Mc[j + 1][k];
            }
            // even j
            {
                double q = qv[j], r = rv8[j];
                double qh = se * r;
                double e  = fma(-q, qh, se);
                double qq = fma(e, r, qh);
                wq[j] = rint(qq) * q;
            }
            // odd j
            {
                double q = qv[j + 1], r = rv8[j + 1];
                double qh = so * r;
                double e  = fma(-q, qh, so);
                double qq = fma(e, r, qh);
                wq[j + 1] = rint(qq) * q;
            }
        }
    }

    // ======== post-cliff: f32 from here on ========
    float wqf[8];
    #pragma unroll
    for (int k = 0; k < 8; ++k) wqf[k] = (float)wq[k];

    // ---- P3: (tq^T row) @ M (f32, even-odd over output index j)
    // a3[j] = pe+po, a3[7-j] = pe-po;  pe from even k, po from odd k.
    float a3[8];
    #pragma unroll
    for (int j = 0; j < 4; ++j) {
        float pe = 0.0f, po = 0.0f;
        #pragma unroll
        for (int k = 0; k < 4; ++k) {
            pe += wqf[2 * k]     * Mcf[2 * k][j];
            po += wqf[2 * k + 1] * Mcf[2 * k + 1][j];
        }
        a3[j]     = pe + po;
        a3[7 - j] = pe - po;
    }

    // ---- Transpose 2 write (f32, pad-9) into MY OWN wave's chunk
    {
        float* tb = (float*)(U + w * 576) + blk * 72 + rr * 9;
        #pragma unroll
        for (int k = 0; k < 8; ++k) tb[k] = a3[k];
    }
    __syncthreads();   // the ONLY barrier: cross-wave channel exchange below

    // ---- Read column rr of A3 for ALL 3 channels (stride-9 f32)
    float tY[8], tU[8], tV[8];
    {
        const float* c0 = (float*)(U + 0 * 576) + blk * 72 + rr;
        const float* c1 = (float*)(U + 1 * 576) + blk * 72 + rr;
        const float* c2 = (float*)(U + 2 * 576) + blk * 72 + rr;
        #pragma unroll
        for (int k = 0; k < 8; ++k) {
            tY[k] = c0[k * 9];
            tU[k] = c1[k * 9];
            tV[k] = c2[k * 9];
        }
    }

    // ---- P4 (f32, even-odd): final IDCT row rr for Y, Cb, Cr
    float yr[8], ur[8], vr[8];
    #pragma unroll
    for (int j = 0; j < 4; ++j) {
        float eY = 0.0f, oY = 0.0f, eU = 0.0f, oU = 0.0f, eV = 0.0f, oV = 0.0f;
        #pragma unroll
        for (int k = 0; k < 4; ++k) {
            float me = Mcf[2 * k][j], mo = Mcf[2 * k + 1][j];
            eY += tY[2 * k] * me;  oY += tY[2 * k + 1] * mo;
            eU += tU[2 * k] * me;  oU += tU[2 * k + 1] * mo;
            eV += tV[2 * k] * me;  oV += tV[2 * k + 1] * mo;
        }
        yr[j] = eY + oY;  yr[7 - j] = eY - oY;
        ur[j] = eU + oU;  ur[7 - j] = eU - oU;
        vr[j] = eV + oV;  vr[7 - j] = eV - oV;
    }

    // ---- Color back (f32, my wave writes plane w), /255, clip, coalesced store
    float* q0 = out + (size_t)(b * 3 + w) * plane + (size_t)(row0 + rr) * 512 + col0 + blk * 8;
    float o[8];
    #pragma unroll
    for (int k = 0; k < 8; ++k) {
        float yd = yr[k] + 128.0f;
        float v;
        if (w == 0)      v = yd + 1.402f * vr[k];
        else if (w == 1) v = yd - 0.34414f * ur[k] - 0.71414f * vr[k];
        else             v = yd + 1.772f * ur[k];
        o[k] = fminf(fmaxf(v * (1.0f / 255.0f), 0.0f), 1.0f);
    }
    *(float4*)(q0)     = make_float4(o[0], o[1], o[2], o[3]);
    *(float4*)(q0 + 4) = make_float4(o[4], o[5], o[6], o[7]);
}

extern "C" void kernel_launch(void* const* d_in, const int* in_sizes, int n_in,
                              void* d_out, int out_size, void* d_ws, size_t ws_size,
                              hipStream_t stream) {
    const float* img     = (const float*)d_in[0];
    const int*   quality = (const int*)d_in[1];
    float*       out     = (float*)d_out;
    // 16 images x 64 row-strips x 8 col-strips = 8192 workgroups x 192 threads
    jpeg_fwd<<<8192, 192, 0, stream>>>(img, quality, out);
}